// Round 1
// baseline (532.310 us; speedup 1.0000x reference)
//
#include <hip/hip_runtime.h>
#include <math.h>

#define EPS  1e-7f
#define MAXT 0.999999f   // 1 - 1e-6

typedef short  s16x8  __attribute__((ext_vector_type(8)));
typedef float  f32x16 __attribute__((ext_vector_type(16)));

__device__ __forceinline__ float waveRedSum(float v) {
    #pragma unroll
    for (int off = 32; off > 0; off >>= 1)
        v += __shfl_xor(v, off, 64);
    return v;
}

__device__ __forceinline__ unsigned short f2bf(float f) {
    unsigned u = __float_as_uint(f);
    u += 0x7fff + ((u >> 16) & 1);          // RNE, inputs are finite
    return (unsigned short)(u >> 16);
}

// ---------------------------------------------------------------------------
// Kernel A: v = log0( h_add( exp0( log0(x) @ embed ), embed_bias ) )
// v written as bf16 in MFMA-B packed layout: V[(k>>4)*2048 + n*16 + (k&15)]
// One wave per row; lane handles cols {2l, 2l+1}.
// ---------------------------------------------------------------------------
__global__ __launch_bounds__(256) void kA(const float* __restrict__ x,
                                          const float* __restrict__ embed,
                                          const float* __restrict__ ebias,
                                          unsigned short* __restrict__ vpack) {
    __shared__ float u[4][128];
    const int wave = threadIdx.x >> 6;
    const int lane = threadIdx.x & 63;
    const int row  = blockIdx.x * 4 + wave;
    const int c0   = lane * 2;

    const float2 xr = *(const float2*)(x + (size_t)row * 128 + c0);

    // log0(x)
    float n2 = waveRedSum(xr.x * xr.x + xr.y * xr.y);
    float n  = fmaxf(sqrtf(n2), EPS);
    float sc = atanhf(fminf(n, MAXT)) / n;
    u[wave][c0]     = xr.x * sc;
    u[wave][c0 + 1] = xr.y * sc;
    __syncthreads();

    // u @ embed
    float a0 = 0.f, a1 = 0.f;
    #pragma unroll 8
    for (int k = 0; k < 128; k++) {
        float  uk = u[wave][k];
        float2 e  = *(const float2*)(embed + (size_t)k * 128 + c0);
        a0 = fmaf(uk, e.x, a0);
        a1 = fmaf(uk, e.y, a1);
    }

    // exp0
    float np2 = waveRedSum(a0 * a0 + a1 * a1);
    float np  = fmaxf(sqrtf(np2), EPS);
    float se  = tanhf(np) / np;
    float h0 = a0 * se, h1 = a1 * se;
    float x2 = np2 * se * se;                    // |h|^2

    // h_add(h, embed_bias)
    float bx = ebias[c0], by = ebias[c0 + 1];
    float xy = waveRedSum(h0 * bx + h1 * by);
    float y2 = waveRedSum(bx * bx + by * by);
    float den = fmaxf(1.f + 2.f * xy + x2 * y2, EPS);
    float cx = 1.f + 2.f * xy + y2;
    float cy = 1.f - x2;
    float hb0 = (cx * h0 + cy * bx) / den;
    float hb1 = (cx * h1 + cy * by) / den;

    // log0(hb)
    float m2 = waveRedSum(hb0 * hb0 + hb1 * hb1);
    float m  = fmaxf(sqrtf(m2), EPS);
    float sl = atanhf(fminf(m, MAXT)) / m;
    float v0 = hb0 * sl, v1 = hb1 * sl;

    const int tbase = (row >> 4) * 2048 + (row & 15);
    vpack[tbase + c0 * 16]       = f2bf(v0);
    vpack[tbase + (c0 + 1) * 16] = f2bf(v1);
}

// ---------------------------------------------------------------------------
// Kernel B: t = adj @ v   (M=8192, N=128, K=8192), bf16 MFMA, fp32 out.
// 256 blocks x 256 threads (4 waves). Block: 32 rows x 128 cols.
// adj staged fp32->bf16 into LDS (coalesced); v read from L2 in packed layout.
// Register prefetch of next K-chunk overlaps HBM with MFMA.
// ---------------------------------------------------------------------------
#define BK 128

__global__ __launch_bounds__(256) void kB(const float* __restrict__ adj,
                                          const unsigned short* __restrict__ vpack,
                                          float* __restrict__ t) {
    __shared__ __align__(16) unsigned short As[32][BK + 8];  // +16B pad per row

    const int tid  = threadIdx.x;
    const int wave = tid >> 6;
    const int lane = tid & 63;
    const int r0   = blockIdx.x * 32;

    // staging assignment: 8 threads per row, 16 floats each
    const int srow = tid >> 3;
    const int scol = (tid & 7) * 16;
    const float* aptr = adj + (size_t)(r0 + srow) * 8192 + scol;

    // fragment indexing
    const int m  = lane & 31;       // output row within tile / LDS row
    const int kh = lane >> 5;       // k-half (0 or 1): k = kh*8 + j
    const int n  = wave * 32 + m;   // output col
    const unsigned short* vb = vpack + (size_t)n * 16 + kh * 8;

    f32x16 acc = {0.f};

    // prefetch first chunk
    float4 f0 = *(const float4*)(aptr + 0);
    float4 f1 = *(const float4*)(aptr + 4);
    float4 f2 = *(const float4*)(aptr + 8);
    float4 f3 = *(const float4*)(aptr + 12);

    for (int kc = 0; kc < 8192; kc += BK) {
        __syncthreads();   // previous compute finished reading As

        // regs -> LDS as bf16
        union { unsigned short u[8]; s16x8 v; } p0, p1;
        p0.u[0] = f2bf(f0.x); p0.u[1] = f2bf(f0.y); p0.u[2] = f2bf(f0.z); p0.u[3] = f2bf(f0.w);
        p0.u[4] = f2bf(f1.x); p0.u[5] = f2bf(f1.y); p0.u[6] = f2bf(f1.z); p0.u[7] = f2bf(f1.w);
        p1.u[0] = f2bf(f2.x); p1.u[1] = f2bf(f2.y); p1.u[2] = f2bf(f2.z); p1.u[3] = f2bf(f2.w);
        p1.u[4] = f2bf(f3.x); p1.u[5] = f2bf(f3.y); p1.u[6] = f2bf(f3.z); p1.u[7] = f2bf(f3.w);
        *(s16x8*)&As[srow][scol]     = p0.v;
        *(s16x8*)&As[srow][scol + 8] = p1.v;
        __syncthreads();

        // issue next chunk's loads (overlap with MFMA below)
        if (kc + BK < 8192) {
            aptr += BK;
            f0 = *(const float4*)(aptr + 0);
            f1 = *(const float4*)(aptr + 4);
            f2 = *(const float4*)(aptr + 8);
            f3 = *(const float4*)(aptr + 12);
        }

        const int ktile0 = kc >> 4;
        #pragma unroll
        for (int kk = 0; kk < BK / 16; kk++) {
            s16x8 a = *(const s16x8*)&As[m][kk * 16 + kh * 8];
            s16x8 b = *(const s16x8*)(vb + (size_t)(ktile0 + kk) * 2048);
            acc = __builtin_amdgcn_mfma_f32_32x32x16_bf16(a, b, acc, 0, 0, 0);
        }
    }

    // epilogue: C/D layout col=lane&31, row=(reg&3)+8*(reg>>2)+4*(lane>>5)
    #pragma unroll
    for (int r = 0; r < 16; r++) {
        int row = r0 + (r & 3) + 8 * (r >> 2) + 4 * kh;
        t[(size_t)row * 128 + n] = acc[r];
    }
}

// ---------------------------------------------------------------------------
// Kernel C: out = h_add( exp0( log0([x ; exp0(t)]) @ layer ), layer_bias )
// One wave per row; lane handles output cols {2l, 2l+1}.
// ---------------------------------------------------------------------------
__global__ __launch_bounds__(256) void kC(const float* __restrict__ x,
                                          const float* __restrict__ t,
                                          const float* __restrict__ layer,
                                          const float* __restrict__ lbias,
                                          float* __restrict__ out) {
    __shared__ float w[4][256];
    const int wave = threadIdx.x >> 6;
    const int lane = threadIdx.x & 63;
    const int row  = blockIdx.x * 4 + wave;
    const int c0   = lane * 2;

    const float2 tr = *(const float2*)(t + (size_t)row * 128 + c0);
    const float2 xr = *(const float2*)(x + (size_t)row * 128 + c0);

    float st = waveRedSum(tr.x * tr.x + tr.y * tr.y);   // |t|^2
    float sx = waveRedSum(xr.x * xr.x + xr.y * xr.y);   // |x|^2

    // neigh = exp0(t) = t * se
    float nt = fmaxf(sqrtf(st), EPS);
    float se = tanhf(nt) / nt;

    // w = log0([x ; neigh])  (norm over the 256-dim concat)
    float ncat2 = sx + st * se * se;
    float ncat  = fmaxf(sqrtf(ncat2), EPS);
    float sw    = atanhf(fminf(ncat, MAXT)) / ncat;
    w[wave][c0]           = xr.x * sw;
    w[wave][c0 + 1]       = xr.y * sw;
    w[wave][128 + c0]     = tr.x * se * sw;
    w[wave][128 + c0 + 1] = tr.y * se * sw;
    __syncthreads();

    // w @ layer
    float a0 = 0.f, a1 = 0.f;
    #pragma unroll 8
    for (int k = 0; k < 256; k++) {
        float  wk = w[wave][k];
        float2 e  = *(const float2*)(layer + (size_t)k * 128 + c0);
        a0 = fmaf(wk, e.x, a0);
        a1 = fmaf(wk, e.y, a1);
    }

    // exp0
    float np2 = waveRedSum(a0 * a0 + a1 * a1);
    float np  = fmaxf(sqrtf(np2), EPS);
    float so  = tanhf(np) / np;
    float o0 = a0 * so, o1 = a1 * so;
    float x2 = np2 * so * so;

    // h_add(o, layer_bias)
    float bx = lbias[c0], by = lbias[c0 + 1];
    float xy = waveRedSum(o0 * bx + o1 * by);
    float y2 = waveRedSum(bx * bx + by * by);
    float den = fmaxf(1.f + 2.f * xy + x2 * y2, EPS);
    float cx = 1.f + 2.f * xy + y2;
    float cy = 1.f - x2;

    float2 res;
    res.x = (cx * o0 + cy * bx) / den;
    res.y = (cx * o1 + cy * by) / den;
    *(float2*)(out + (size_t)row * 128 + c0) = res;
}

// ---------------------------------------------------------------------------
extern "C" void kernel_launch(void* const* d_in, const int* in_sizes, int n_in,
                              void* d_out, int out_size, void* d_ws, size_t ws_size,
                              hipStream_t stream) {
    const float* x     = (const float*)d_in[0];   // [8192,128]
    const float* adj   = (const float*)d_in[1];   // [8192,8192]
    const float* embed = (const float*)d_in[2];   // [128,128]
    const float* layer = (const float*)d_in[3];   // [256,128]
    const float* eb    = (const float*)d_in[4];   // [128]
    const float* lb    = (const float*)d_in[5];   // [128]
    float* out = (float*)d_out;

    unsigned short* vpack = (unsigned short*)d_ws;                 // 2 MB bf16 packed
    float* t = (float*)((char*)d_ws + 8192 * 128 * sizeof(unsigned short)); // 4 MB fp32

    kA<<<2048, 256, 0, stream>>>(x, embed, eb, vpack);
    kB<<<256,  256, 0, stream>>>(adj, vpack, t);
    kC<<<2048, 256, 0, stream>>>(x, t, layer, lb, out);
}

// Round 2
// 499.345 us; speedup vs baseline: 1.0660x; 1.0660x over previous
//
#include <hip/hip_runtime.h>
#include <math.h>

#define EPS  1e-7f
#define MAXT 0.999999f   // 1 - 1e-6

typedef short  s16x8  __attribute__((ext_vector_type(8)));
typedef float  f32x16 __attribute__((ext_vector_type(16)));

__device__ __forceinline__ float waveRedSum(float v) {
    #pragma unroll
    for (int off = 32; off > 0; off >>= 1)
        v += __shfl_xor(v, off, 64);
    return v;
}

__device__ __forceinline__ unsigned short f2bf(float f) {
    unsigned u = __float_as_uint(f);
    u += 0x7fff + ((u >> 16) & 1);          // RNE, inputs are finite
    return (unsigned short)(u >> 16);
}

// ---------------------------------------------------------------------------
// Kernel A: v = log0( h_add( exp0( log0(x) @ embed ), embed_bias ) )
// v written as bf16 in MFMA-B packed layout: V[(k>>4)*2048 + n*16 + (k&15)]
// One wave per row; lane handles cols {2l, 2l+1}.
// ---------------------------------------------------------------------------
__global__ __launch_bounds__(256) void kA(const float* __restrict__ x,
                                          const float* __restrict__ embed,
                                          const float* __restrict__ ebias,
                                          unsigned short* __restrict__ vpack) {
    __shared__ float u[4][128];
    const int wave = threadIdx.x >> 6;
    const int lane = threadIdx.x & 63;
    const int row  = blockIdx.x * 4 + wave;
    const int c0   = lane * 2;

    const float2 xr = *(const float2*)(x + (size_t)row * 128 + c0);

    // log0(x)
    float n2 = waveRedSum(xr.x * xr.x + xr.y * xr.y);
    float n  = fmaxf(sqrtf(n2), EPS);
    float sc = atanhf(fminf(n, MAXT)) / n;
    u[wave][c0]     = xr.x * sc;
    u[wave][c0 + 1] = xr.y * sc;
    __syncthreads();

    // u @ embed
    float a0 = 0.f, a1 = 0.f;
    #pragma unroll 8
    for (int k = 0; k < 128; k++) {
        float  uk = u[wave][k];
        float2 e  = *(const float2*)(embed + (size_t)k * 128 + c0);
        a0 = fmaf(uk, e.x, a0);
        a1 = fmaf(uk, e.y, a1);
    }

    // exp0
    float np2 = waveRedSum(a0 * a0 + a1 * a1);
    float np  = fmaxf(sqrtf(np2), EPS);
    float se  = tanhf(np) / np;
    float h0 = a0 * se, h1 = a1 * se;
    float x2 = np2 * se * se;                    // |h|^2

    // h_add(h, embed_bias)
    float bx = ebias[c0], by = ebias[c0 + 1];
    float xy = waveRedSum(h0 * bx + h1 * by);
    float y2 = waveRedSum(bx * bx + by * by);
    float den = fmaxf(1.f + 2.f * xy + x2 * y2, EPS);
    float cx = 1.f + 2.f * xy + y2;
    float cy = 1.f - x2;
    float hb0 = (cx * h0 + cy * bx) / den;
    float hb1 = (cx * h1 + cy * by) / den;

    // log0(hb)
    float m2 = waveRedSum(hb0 * hb0 + hb1 * hb1);
    float m  = fmaxf(sqrtf(m2), EPS);
    float sl = atanhf(fminf(m, MAXT)) / m;
    float v0 = hb0 * sl, v1 = hb1 * sl;

    const int tbase = (row >> 4) * 2048 + (row & 15);
    vpack[tbase + c0 * 16]       = f2bf(v0);
    vpack[tbase + (c0 + 1) * 16] = f2bf(v1);
}

// ---------------------------------------------------------------------------
// Kernel B: t = adj @ v   (M=8192, N=128, K=8192), bf16 MFMA, fp32 out.
// K split S ways across blockIdx.y (8 blocks/CU -> latency hiding via block
// interleave; the __syncthreads vmcnt(0) drain per iter is covered by the
// other 7 resident blocks). Each split writes a private fp32 partial slice.
// ---------------------------------------------------------------------------
#define BK 128

__global__ __launch_bounds__(256) void kB(const float* __restrict__ adj,
                                          const unsigned short* __restrict__ vpack,
                                          float* __restrict__ tpart,
                                          int klen) {
    __shared__ __align__(16) unsigned short As[32][BK + 8];  // +16B pad per row

    const int tid  = threadIdx.x;
    const int wave = tid >> 6;
    const int lane = tid & 63;
    const int r0   = blockIdx.x * 32;
    const int k0   = blockIdx.y * klen;
    float* tout    = tpart + (size_t)blockIdx.y * 8192 * 128;

    // staging assignment: 8 threads per row, 16 floats each
    const int srow = tid >> 3;
    const int scol = (tid & 7) * 16;
    const float* aptr = adj + (size_t)(r0 + srow) * 8192 + k0 + scol;

    // fragment indexing
    const int m  = lane & 31;       // output row within tile / LDS row
    const int kh = lane >> 5;       // k-half (0 or 1): k = kh*8 + j
    const int n  = wave * 32 + m;   // output col
    const unsigned short* vb = vpack + (size_t)n * 16 + kh * 8;

    f32x16 acc = {0.f};

    // prefetch first chunk
    float4 f0 = *(const float4*)(aptr + 0);
    float4 f1 = *(const float4*)(aptr + 4);
    float4 f2 = *(const float4*)(aptr + 8);
    float4 f3 = *(const float4*)(aptr + 12);

    const int kiters = klen / BK;
    for (int it = 0; it < kiters; it++) {
        __syncthreads();   // previous compute finished reading As

        // regs -> LDS as bf16
        union { unsigned short u[8]; s16x8 v; } p0, p1;
        p0.u[0] = f2bf(f0.x); p0.u[1] = f2bf(f0.y); p0.u[2] = f2bf(f0.z); p0.u[3] = f2bf(f0.w);
        p0.u[4] = f2bf(f1.x); p0.u[5] = f2bf(f1.y); p0.u[6] = f2bf(f1.z); p0.u[7] = f2bf(f1.w);
        p1.u[0] = f2bf(f2.x); p1.u[1] = f2bf(f2.y); p1.u[2] = f2bf(f2.z); p1.u[3] = f2bf(f2.w);
        p1.u[4] = f2bf(f3.x); p1.u[5] = f2bf(f3.y); p1.u[6] = f2bf(f3.z); p1.u[7] = f2bf(f3.w);
        *(s16x8*)&As[srow][scol]     = p0.v;
        *(s16x8*)&As[srow][scol + 8] = p1.v;
        __syncthreads();

        // issue next chunk's loads (overlap with MFMA below)
        if (it + 1 < kiters) {
            aptr += BK;
            f0 = *(const float4*)(aptr + 0);
            f1 = *(const float4*)(aptr + 4);
            f2 = *(const float4*)(aptr + 8);
            f3 = *(const float4*)(aptr + 12);
        }

        const int ktile0 = (k0 + it * BK) >> 4;
        #pragma unroll
        for (int kk = 0; kk < BK / 16; kk++) {
            s16x8 a = *(const s16x8*)&As[m][kk * 16 + kh * 8];
            s16x8 b = *(const s16x8*)(vb + (size_t)(ktile0 + kk) * 2048);
            acc = __builtin_amdgcn_mfma_f32_32x32x16_bf16(a, b, acc, 0, 0, 0);
        }
    }

    // epilogue: C/D layout col=lane&31, row=(reg&3)+8*(reg>>2)+4*(lane>>5)
    #pragma unroll
    for (int r = 0; r < 16; r++) {
        int row = r0 + (r & 3) + 8 * (r >> 2) + 4 * kh;
        tout[(size_t)row * 128 + n] = acc[r];
    }
}

// ---------------------------------------------------------------------------
// Kernel C: out = h_add( exp0( log0([x ; exp0(t)]) @ layer ), layer_bias )
// Sums the S partial slices of t, then one wave per row; lane = cols {2l,2l+1}.
// ---------------------------------------------------------------------------
__global__ __launch_bounds__(256) void kC(const float* __restrict__ x,
                                          const float* __restrict__ tpart,
                                          const float* __restrict__ layer,
                                          const float* __restrict__ lbias,
                                          float* __restrict__ out,
                                          int S) {
    __shared__ float w[4][256];
    const int wave = threadIdx.x >> 6;
    const int lane = threadIdx.x & 63;
    const int row  = blockIdx.x * 4 + wave;
    const int c0   = lane * 2;

    float2 tr = *(const float2*)(tpart + (size_t)row * 128 + c0);
    for (int s = 1; s < S; s++) {
        float2 p = *(const float2*)(tpart + (size_t)s * 8192 * 128 + (size_t)row * 128 + c0);
        tr.x += p.x; tr.y += p.y;
    }
    const float2 xr = *(const float2*)(x + (size_t)row * 128 + c0);

    float st = waveRedSum(tr.x * tr.x + tr.y * tr.y);   // |t|^2
    float sx = waveRedSum(xr.x * xr.x + xr.y * xr.y);   // |x|^2

    // neigh = exp0(t) = t * se
    float nt = fmaxf(sqrtf(st), EPS);
    float se = tanhf(nt) / nt;

    // w = log0([x ; neigh])  (norm over the 256-dim concat)
    float ncat2 = sx + st * se * se;
    float ncat  = fmaxf(sqrtf(ncat2), EPS);
    float sw    = atanhf(fminf(ncat, MAXT)) / ncat;
    w[wave][c0]           = xr.x * sw;
    w[wave][c0 + 1]       = xr.y * sw;
    w[wave][128 + c0]     = tr.x * se * sw;
    w[wave][128 + c0 + 1] = tr.y * se * sw;
    __syncthreads();

    // w @ layer
    float a0 = 0.f, a1 = 0.f;
    #pragma unroll 8
    for (int k = 0; k < 256; k++) {
        float  wk = w[wave][k];
        float2 e  = *(const float2*)(layer + (size_t)k * 128 + c0);
        a0 = fmaf(wk, e.x, a0);
        a1 = fmaf(wk, e.y, a1);
    }

    // exp0
    float np2 = waveRedSum(a0 * a0 + a1 * a1);
    float np  = fmaxf(sqrtf(np2), EPS);
    float so  = tanhf(np) / np;
    float o0 = a0 * so, o1 = a1 * so;
    float x2 = np2 * so * so;

    // h_add(o, layer_bias)
    float bx = lbias[c0], by = lbias[c0 + 1];
    float xy = waveRedSum(o0 * bx + o1 * by);
    float y2 = waveRedSum(bx * bx + by * by);
    float den = fmaxf(1.f + 2.f * xy + x2 * y2, EPS);
    float cx = 1.f + 2.f * xy + y2;
    float cy = 1.f - x2;

    float2 res;
    res.x = (cx * o0 + cy * bx) / den;
    res.y = (cx * o1 + cy * by) / den;
    *(float2*)(out + (size_t)row * 128 + c0) = res;
}

// ---------------------------------------------------------------------------
extern "C" void kernel_launch(void* const* d_in, const int* in_sizes, int n_in,
                              void* d_out, int out_size, void* d_ws, size_t ws_size,
                              hipStream_t stream) {
    const float* x     = (const float*)d_in[0];   // [8192,128]
    const float* adj   = (const float*)d_in[1];   // [8192,8192]
    const float* embed = (const float*)d_in[2];   // [128,128]
    const float* layer = (const float*)d_in[3];   // [256,128]
    const float* eb    = (const float*)d_in[4];   // [128]
    const float* lb    = (const float*)d_in[5];   // [128]
    float* out = (float*)d_out;

    const size_t vbytes = (size_t)8192 * 128 * 2;          // 2 MB bf16 packed
    const size_t slice  = (size_t)8192 * 128 * 4;          // 4 MB fp32 partial

    int S = 1;
    if      (ws_size >= vbytes + 8 * slice) S = 8;
    else if (ws_size >= vbytes + 4 * slice) S = 4;
    else if (ws_size >= vbytes + 2 * slice) S = 2;

    unsigned short* vpack = (unsigned short*)d_ws;
    float* tpart = (float*)((char*)d_ws + vbytes);

    kA<<<2048, 256, 0, stream>>>(x, embed, eb, vpack);
    kB<<<dim3(256, S), 256, 0, stream>>>(adj, vpack, tpart, 8192 / S);
    kC<<<2048, 256, 0, stream>>>(x, tpart, layer, lb, out, S);
}